// Round 12
// baseline (36.931 us; speedup 1.0000x reference)
//
#include <hip/hip_runtime.h>
#include <math.h>

#define BB 32
#define SS 2048
#define HH 128
#define AA 8

typedef _Float16 h2 __attribute__((ext_vector_type(2)));
typedef _Float16 h8 __attribute__((ext_vector_type(8)));
typedef _Float16 f16x8 __attribute__((ext_vector_type(8)));
typedef float f32x4 __attribute__((ext_vector_type(4)));

// ws layout:
//   bfrag:  [12][64] uint4 (12288 B) — u prepacked as MFMA B-fragments:
//           bfrag[kk][lane] elem j = B[k][c], k = kk*32+(lane>>4)*8+j
//           (k = w*128+d), c = lane&15 (zero for c>=8)
//   E:      [B][A][S]     524288 floats (masked exp(score), unnormalized)
//   Zpart:  [B][A][32]    8192
//   pools:  [B][32][A][H] 1048576 (unnormalized partial context sums)

// 32 blocks = (a 0..7) x (dchunk 0..3); coalesced LDS staging of proj chunk.
// u-sum order (h ascending, one thread per (d,w)) identical to prior rounds.
__global__ __launch_bounds__(128) void prep_kernel(const float* __restrict__ embed,
                                                   const float* __restrict__ proj,
                                                   uint4* __restrict__ bfrag) {
    __shared__ float pl[32][129];   // proj[a][dc*32+r][h]
    __shared__ float eb[384];
    __shared__ float ub[32][3];
    int t = threadIdx.x;
    int a = blockIdx.x >> 2, dc = blockIdx.x & 3;

    for (int i = t; i < 32 * 128; i += 128) {
        int r = i >> 7, h = i & 127;
        pl[r][h] = proj[((size_t)a * HH + dc * 32 + r) * HH + h];  // coalesced
    }
    for (int i = t; i < 384; i += 128) eb[i] = embed[a * 384 + i];
    __syncthreads();

    if (t < 96) {
        int w = t / 32, dl = t % 32;
        float acc = 0.f;
        for (int h = 0; h < HH; ++h) acc += pl[dl][h] * eb[h * 3 + w];
        ub[dl][w] = acc;
    }
    __syncthreads();

    // 24 bfrag entries owned by this (a, dc): kk in {dc, dc+4, dc+8}, 8 e each
    if (t < 24) {
        int kk = dc + (t >> 3) * 4, e = t & 7;
        f16x8 v = {0, 0, 0, 0, 0, 0, 0, 0};
        int lane;
        if (e < 4) {
            int q = e;
            lane = q * 16 + a;
            int w = kk >> 2;
            #pragma unroll
            for (int j = 0; j < 8; ++j) v[j] = (_Float16)ub[q * 8 + j][w];
        } else {
            lane = (e - 4) * 16 + a + 8;   // zero columns 8..15
        }
        bfrag[kk * 64 + lane] = __builtin_bit_cast(uint4, v);
    }
}

// Per (b, 64-s tile): scores via MFMA (A = f16 doc windows from LDS,
// B = prepacked u fragments) -> E = mask*exp(score), Zpart, unnormalized
// pooled context sums. Max-free exp is safe: |score| < ~0.2.
__global__ __launch_bounds__(256, 4) void tile_kernel(const float* __restrict__ doc,
                                                      const int* __restrict__ mask,
                                                      const uint4* __restrict__ bfrag,
                                                      float* __restrict__ E,
                                                      float* __restrict__ Zpart,
                                                      float* __restrict__ pools) {
    // dt [66][72] h2 (19008 B) + etile [64][8] f32 (2048) + zred [8][8] (256)
    __shared__ __align__(16) unsigned char smraw[21312];
    h2*    dt    = (h2*)smraw;
    float* etile = (float*)(smraw + 19008);
    float* zred  = (float*)(smraw + 19008 + 2048);

    int t = threadIdx.x;
    int lane = t & 63, wave = t >> 6;
    int tile = blockIdx.x;   // 0..31, 64 s each
    int b = blockIdx.y;
    int s0 = tile * 64;

    // ---- stage rows s0-1 .. s0+64 as f16 (zero outside [0,S)), stride 72 h2 ----
    for (int idx = t; idx < 66 * 16; idx += 256) {
        int row = idx >> 4, c = idx & 15;   // c: 8-float chunk
        int srow = s0 - 1 + row;
        h8 hv = {0, 0, 0, 0, 0, 0, 0, 0};
        if (srow >= 0 && srow < SS) {
            const float4* src = (const float4*)(doc + ((size_t)b * SS + srow) * HH + c * 8);
            float4 v0 = src[0], v1 = src[1];
            hv[0] = (_Float16)v0.x; hv[1] = (_Float16)v0.y;
            hv[2] = (_Float16)v0.z; hv[3] = (_Float16)v0.w;
            hv[4] = (_Float16)v1.x; hv[5] = (_Float16)v1.y;
            hv[6] = (_Float16)v1.z; hv[7] = (_Float16)v1.w;
        }
        *(h8*)(dt + row * 72 + c * 4) = hv;
    }

    // ---- B fragments: 12 x 16B per lane (L2-hot; same for all blocks) ----
    f16x8 bf[12];
    #pragma unroll
    for (int kk = 0; kk < 12; ++kk)
        bf[kk] = __builtin_bit_cast(f16x8, bfrag[kk * 64 + lane]);
    __syncthreads();   // dt ready

    // ---- scores: wave covers s rows wave*16 .. wave*16+15 ----
    f32x4 acc = {0.f, 0.f, 0.f, 0.f};
    #pragma unroll
    for (int kk = 0; kk < 12; ++kk) {
        int w = kk >> 2;
        int row = wave * 16 + (lane & 15) + w;
        int colh2 = (kk & 3) * 16 + (lane >> 4) * 4;
        f16x8 af = *(const f16x8*)(dt + row * 72 + colh2);
        acc = __builtin_amdgcn_mfma_f32_16x16x32_f16(af, bf[kk], acc, 0, 0, 0);
    }

    // D layout: col = lane&15 (aspect), row = (lane>>4)*4 + reg (s in 16-block)
    const int* mrow = mask + (size_t)b * SS + s0;
    {
        int a = lane & 15;
        int rbase = wave * 16 + (lane >> 4) * 4;
        if (a < 8) {
            float4 ev;
            float* evp = (float*)&ev;
            #pragma unroll
            for (int jj = 0; jj < 4; ++jj) {
                int sl2 = rbase + jj;
                float e = mrow[sl2] ? __expf(acc[jj]) : 0.f;
                evp[jj] = e;
                etile[sl2 * 8 + a] = e;
            }
            *(float4*)(E + ((size_t)(b * AA + a)) * SS + s0 + rbase) = ev;
        }
    }
    __syncthreads();
    if (t < 64) {
        int a = t & 7, g = t >> 3;
        float p = 0.f;
        #pragma unroll
        for (int k = 0; k < 8; ++k) p += etile[(g * 8 + k) * 8 + a];
        zred[g * 8 + a] = p;
    }
    __syncthreads();
    if (t < 8) {
        float z = 0.f;
        #pragma unroll
        for (int g = 0; g < 8; ++g) z += zred[g * 8 + t];
        Zpart[((size_t)(b * AA + t)) * 32 + tile] = z;
    }

    // ---- pool from f16 LDS: thread (dq, sub); d = dq*4, s = sub*8 + i ----
    int dq = t & 31, sub = t >> 5;
    float4 pacc[8];
    #pragma unroll
    for (int a = 0; a < 8; ++a) pacc[a] = make_float4(0.f, 0.f, 0.f, 0.f);
    for (int i = 0; i < 8; ++i) {
        int row = 1 + sub * 8 + i;
        uint2 X = *(const uint2*)(dt + row * 72 + dq * 2);
        h2 lo = __builtin_bit_cast(h2, X.x), hi = __builtin_bit_cast(h2, X.y);
        float x0 = (float)lo[0], x1 = (float)lo[1];
        float x2 = (float)hi[0], x3 = (float)hi[1];
        #pragma unroll
        for (int a = 0; a < 8; ++a) {
            float w = etile[(sub * 8 + i) * 8 + a];
            pacc[a].x += w * x0; pacc[a].y += w * x1;
            pacc[a].z += w * x2; pacc[a].w += w * x3;
        }
    }
    // pair-reduce subs 2k (lanes<32) + 2k+1 (lanes>=32) within each wave
    #pragma unroll
    for (int a = 0; a < 8; ++a) {
        pacc[a].x += __shfl_xor(pacc[a].x, 32);
        pacc[a].y += __shfl_xor(pacc[a].y, 32);
        pacc[a].z += __shfl_xor(pacc[a].z, 32);
        pacc[a].w += __shfl_xor(pacc[a].w, 32);
    }
    __syncthreads();   // all dt reads done -> reuse as cs2
    float* cs2 = (float*)smraw;   // [4 wave][8 a][128 d] = 16384 B < 19008 B
    if ((t & 63) < 32) {
        #pragma unroll
        for (int a = 0; a < 8; ++a)
            *(float4*)(cs2 + (wave * 8 + a) * 128 + dq * 4) = pacc[a];
    }
    __syncthreads();
    for (int oi = t; oi < 1024; oi += 256) {
        int a = oi >> 7, d = oi & 127;
        float v = (cs2[(0 * 8 + a) * 128 + d] + cs2[(1 * 8 + a) * 128 + d]) +
                  (cs2[(2 * 8 + a) * 128 + d] + cs2[(3 * 8 + a) * 128 + d]);
        pools[(((size_t)(b * 32 + tile)) * AA + a) * HH + d] = v;
    }
}

// 1D grid of 1024+256 blocks.
//   id < 1024 : attn chunk (b = id>>5, ck = id&31): attn = E*invZ, float4 I/O.
//   id >= 1024: rep for (b,a) = ((id-1024)>>3, (id-1024)&7): full 128-h slice,
//               pools/proj read once (was 4x redundant).
__global__ __launch_bounds__(256) void finalize_kernel(const float* __restrict__ E,
                                                       const float* __restrict__ Zpart,
                                                       const float* __restrict__ pools,
                                                       const float* __restrict__ proj,
                                                       float* __restrict__ attn,
                                                       float* __restrict__ rep) {
    int t = threadIdx.x;
    int id = blockIdx.x;

    if (id < 1024) {
        __shared__ float zbuf[256];
        __shared__ float invZ[8];
        int b = id >> 5, ck = id & 31;
        zbuf[t] = Zpart[((size_t)(b * AA + (t >> 5))) * 32 + (t & 31)];
        __syncthreads();
        if (t < 8) {
            float z = 0.f;
            #pragma unroll
            for (int k = 0; k < 32; ++k) z += zbuf[t * 32 + k];
            invZ[t] = 1.0f / z;
        }
        __syncthreads();
        if (t < 128) {
            int a = t >> 4, s4 = (t & 15) * 4;
            size_t idx = ((size_t)(b * AA + a)) * SS + ck * 64 + s4;
            float4 ev = *(const float4*)(E + idx);
            float iz = invZ[a];
            ev.x *= iz; ev.y *= iz; ev.z *= iz; ev.w *= iz;
            *(float4*)(attn + idx) = ev;
        }
        return;
    }

    {
        __shared__ float invz;
        __shared__ float ctxp[2][128];
        __shared__ float ctx[128];
        __shared__ float hred[2][128];
        int r = id - 1024;
        int b = r >> 3, a = r & 7;
        if (t == 0) {
            float z = 0.f;
            for (int k = 0; k < 32; ++k)
                z += Zpart[((size_t)(b * AA + a)) * 32 + k];
            invz = 1.0f / z;
        }
        {
            int d = t & 127, half = t >> 7;
            float v = 0.f;
            for (int c = half * 16; c < half * 16 + 16; ++c)
                v += pools[(((size_t)(b * 32 + c)) * AA + a) * HH + d];
            ctxp[half][d] = v;
        }
        __syncthreads();
        if (t < 128) ctx[t] = (ctxp[0][t] + ctxp[1][t]) * invz;
        __syncthreads();
        {
            int h = t & 127, dh = t >> 7;
            float v = 0.f;
            for (int d = dh * 64; d < dh * 64 + 64; ++d)
                v += ctx[d] * proj[((size_t)a * HH + d) * HH + h];
            hred[dh][h] = v;
        }
        __syncthreads();
        if (t < 128)
            rep[((size_t)(b * AA + a)) * HH + t] = hred[0][t] + hred[1][t];
    }
}

extern "C" void kernel_launch(void* const* d_in, const int* in_sizes, int n_in,
                              void* d_out, int out_size, void* d_ws, size_t ws_size,
                              hipStream_t stream) {
    const float* doc   = (const float*)d_in[0];   // [32][2048][128]
    const int*   mask  = (const int*)d_in[1];     // [32][2048]
    const float* embed = (const float*)d_in[2];   // [8][384]
    const float* proj  = (const float*)d_in[3];   // [8][128][128]

    float* out  = (float*)d_out;
    float* attn = out;                             // [32][8][2048]
    float* rep  = out + (size_t)BB * AA * SS;      // [32][8][128]

    uint4* bfrag = (uint4*)d_ws;                   // 12288 B of the 16 KB slot
    float* E     = (float*)d_ws + 4096;
    float* Zp    = E + (size_t)BB * AA * SS;
    float* pools = Zp + (size_t)BB * AA * 32;

    prep_kernel<<<32, 128, 0, stream>>>(embed, proj, bfrag);
    tile_kernel<<<dim3(32, 32), 256, 0, stream>>>(doc, mask, bfrag, E, Zp, pools);
    finalize_kernel<<<1280, 256, 0, stream>>>(E, Zp, pools, proj, attn, rep);
}

// Round 13
// 28.974 us; speedup vs baseline: 1.2746x; 1.2746x over previous
//
#include <hip/hip_runtime.h>
#include <math.h>

#define BB 32
#define SS 2048
#define HH 128
#define AA 8

typedef _Float16 h2 __attribute__((ext_vector_type(2)));
typedef _Float16 h8 __attribute__((ext_vector_type(8)));
typedef _Float16 f16x8 __attribute__((ext_vector_type(8)));
typedef float f32x4 __attribute__((ext_vector_type(4)));

// ws layout:
//   bfrag:  [12][64] uint4 (12288 B) — u prepacked as MFMA B-fragments:
//           bfrag[kk][lane] elem j = B[k][c], k = kk*32+(lane>>4)*8+j
//           (k = w*128+d), c = lane&15 (zero for c>=8)
//   E:      [B][A][S]     524288 floats (masked exp(score), unnormalized)
//   Zpart:  [B][A][32]    8192
//   pools:  [B][32][A][H] 1048576 (unnormalized partial context sums)

// R11-proven prep: 8 blocks x 128 threads. Block a: u_a[d][w], then the bfrag
// entries for lanes with c==a (real) and c==a+8 (zeros).
__global__ __launch_bounds__(128) void prep_kernel(const float* __restrict__ embed,
                                                   const float* __restrict__ proj,
                                                   uint4* __restrict__ bfrag) {
    __shared__ float ua[HH][3];   // u for this aspect: [d][w]
    int a = blockIdx.x;           // 0..7
    int d = threadIdx.x;          // 0..127
    const float* P = proj + ((size_t)a * HH + d) * HH;  // aspProj[a][d][:]
    const float* E = embed + a * (3 * HH);              // embedR[a][h][w] = E[h*3+w]
    float a0 = 0.f, a1 = 0.f, a2 = 0.f;
    for (int h = 0; h < HH; ++h) {
        float x = P[h];
        a0 += x * E[h * 3 + 0];   // E loads wave-uniform -> scalar cache
        a1 += x * E[h * 3 + 1];
        a2 += x * E[h * 3 + 2];
    }
    ua[d][0] = a0; ua[d][1] = a1; ua[d][2] = a2;
    __syncthreads();

    // 96 fragment entries for this block: i = kk*8 + e; e<4 -> lane q*16+a
    // (real), e>=4 -> lane (e-4)*16 + a + 8 (zero pad).
    for (int i = d; i < 96; i += 128) {
        int kk = i >> 3, e = i & 7;
        f16x8 v = {0, 0, 0, 0, 0, 0, 0, 0};
        int lane;
        if (e < 4) {
            int q = e;
            lane = q * 16 + a;
            #pragma unroll
            for (int j = 0; j < 8; ++j) {
                int k = kk * 32 + q * 8 + j;
                int w = k >> 7, dd = k & 127;
                v[j] = (_Float16)ua[dd][w];
            }
        } else {
            lane = (e - 4) * 16 + a + 8;   // zero columns 8..15
        }
        bfrag[kk * 64 + lane] = __builtin_bit_cast(uint4, v);
    }
}

// Per (b, 64-s tile): scores via MFMA (A = f16 doc windows from LDS,
// B = prepacked u fragments) -> E = mask*exp(score), Zpart, unnormalized
// pooled context sums. Max-free exp is safe: |score| < ~0.2.
// Only change vs R11: E written as one float4 per (a, rbase) instead of 4
// scalar stores (attribution experiment for R12's regression).
__global__ __launch_bounds__(256, 4) void tile_kernel(const float* __restrict__ doc,
                                                      const int* __restrict__ mask,
                                                      const uint4* __restrict__ bfrag,
                                                      float* __restrict__ E,
                                                      float* __restrict__ Zpart,
                                                      float* __restrict__ pools) {
    // dt [66][72] h2 (19008 B) + etile [64][8] f32 (2048) + zred [8][8] (256)
    __shared__ __align__(16) unsigned char smraw[21312];
    h2*    dt    = (h2*)smraw;
    float* etile = (float*)(smraw + 19008);
    float* zred  = (float*)(smraw + 19008 + 2048);

    int t = threadIdx.x;
    int lane = t & 63, wave = t >> 6;
    int tile = blockIdx.x;   // 0..31, 64 s each
    int b = blockIdx.y;
    int s0 = tile * 64;

    // ---- stage rows s0-1 .. s0+64 as f16 (zero outside [0,S)), stride 72 h2 ----
    for (int idx = t; idx < 66 * 16; idx += 256) {
        int row = idx >> 4, c = idx & 15;   // c: 8-float chunk
        int srow = s0 - 1 + row;
        h8 hv = {0, 0, 0, 0, 0, 0, 0, 0};
        if (srow >= 0 && srow < SS) {
            const float4* src = (const float4*)(doc + ((size_t)b * SS + srow) * HH + c * 8);
            float4 v0 = src[0], v1 = src[1];
            hv[0] = (_Float16)v0.x; hv[1] = (_Float16)v0.y;
            hv[2] = (_Float16)v0.z; hv[3] = (_Float16)v0.w;
            hv[4] = (_Float16)v1.x; hv[5] = (_Float16)v1.y;
            hv[6] = (_Float16)v1.z; hv[7] = (_Float16)v1.w;
        }
        *(h8*)(dt + row * 72 + c * 4) = hv;
    }

    // ---- B fragments: 12 x 16B per lane (L2-hot; same for all blocks) ----
    f16x8 bf[12];
    #pragma unroll
    for (int kk = 0; kk < 12; ++kk)
        bf[kk] = __builtin_bit_cast(f16x8, bfrag[kk * 64 + lane]);
    __syncthreads();   // dt ready

    // ---- scores: wave covers s rows wave*16 .. wave*16+15 ----
    f32x4 acc = {0.f, 0.f, 0.f, 0.f};
    #pragma unroll
    for (int kk = 0; kk < 12; ++kk) {
        int w = kk >> 2;
        int row = wave * 16 + (lane & 15) + w;
        int colh2 = (kk & 3) * 16 + (lane >> 4) * 4;
        f16x8 af = *(const f16x8*)(dt + row * 72 + colh2);
        acc = __builtin_amdgcn_mfma_f32_16x16x32_f16(af, bf[kk], acc, 0, 0, 0);
    }

    // D layout: col = lane&15 (aspect), row = (lane>>4)*4 + reg (s in 16-block)
    const int* mrow = mask + (size_t)b * SS + s0;
    {
        int a = lane & 15;
        int rbase = wave * 16 + (lane >> 4) * 4;
        if (a < 8) {
            float4 ev;
            float* evp = (float*)&ev;
            #pragma unroll
            for (int jj = 0; jj < 4; ++jj) {
                int sl2 = rbase + jj;
                float e = mrow[sl2] ? __expf(acc[jj]) : 0.f;
                evp[jj] = e;
                etile[sl2 * 8 + a] = e;
            }
            *(float4*)(E + ((size_t)(b * AA + a)) * SS + s0 + rbase) = ev;
        }
    }
    __syncthreads();
    if (t < 64) {
        int a = t & 7, g = t >> 3;
        float p = 0.f;
        #pragma unroll
        for (int k = 0; k < 8; ++k) p += etile[(g * 8 + k) * 8 + a];
        zred[g * 8 + a] = p;
    }
    __syncthreads();
    if (t < 8) {
        float z = 0.f;
        #pragma unroll
        for (int g = 0; g < 8; ++g) z += zred[g * 8 + t];
        Zpart[((size_t)(b * AA + t)) * 32 + tile] = z;
    }

    // ---- pool from f16 LDS: thread (dq, sub); d = dq*4, s = sub*8 + i ----
    int dq = t & 31, sub = t >> 5;
    float4 pacc[8];
    #pragma unroll
    for (int a = 0; a < 8; ++a) pacc[a] = make_float4(0.f, 0.f, 0.f, 0.f);
    for (int i = 0; i < 8; ++i) {
        int row = 1 + sub * 8 + i;
        uint2 X = *(const uint2*)(dt + row * 72 + dq * 2);
        h2 lo = __builtin_bit_cast(h2, X.x), hi = __builtin_bit_cast(h2, X.y);
        float x0 = (float)lo[0], x1 = (float)lo[1];
        float x2 = (float)hi[0], x3 = (float)hi[1];
        #pragma unroll
        for (int a = 0; a < 8; ++a) {
            float w = etile[(sub * 8 + i) * 8 + a];
            pacc[a].x += w * x0; pacc[a].y += w * x1;
            pacc[a].z += w * x2; pacc[a].w += w * x3;
        }
    }
    // pair-reduce subs 2k (lanes<32) + 2k+1 (lanes>=32) within each wave
    #pragma unroll
    for (int a = 0; a < 8; ++a) {
        pacc[a].x += __shfl_xor(pacc[a].x, 32);
        pacc[a].y += __shfl_xor(pacc[a].y, 32);
        pacc[a].z += __shfl_xor(pacc[a].z, 32);
        pacc[a].w += __shfl_xor(pacc[a].w, 32);
    }
    __syncthreads();   // all dt reads done -> reuse as cs2
    float* cs2 = (float*)smraw;   // [4 wave][8 a][128 d] = 16384 B < 19008 B
    if ((t & 63) < 32) {
        #pragma unroll
        for (int a = 0; a < 8; ++a)
            *(float4*)(cs2 + (wave * 8 + a) * 128 + dq * 4) = pacc[a];
    }
    __syncthreads();
    for (int oi = t; oi < 1024; oi += 256) {
        int a = oi >> 7, d = oi & 127;
        float v = (cs2[(0 * 8 + a) * 128 + d] + cs2[(1 * 8 + a) * 128 + d]) +
                  (cs2[(2 * 8 + a) * 128 + d] + cs2[(3 * 8 + a) * 128 + d]);
        pools[(((size_t)(b * 32 + tile)) * AA + a) * HH + d] = v;
    }
}

// R11-proven finalize: per (b, chunk): invZ from Zpart; attn = E*invZ for the
// 64-s chunk; plus a 32-h slice of rep for aspect a = chunk&7 (hq = chunk>>3).
__global__ __launch_bounds__(256) void finalize_kernel(const float* __restrict__ E,
                                                       const float* __restrict__ Zpart,
                                                       const float* __restrict__ pools,
                                                       const float* __restrict__ proj,
                                                       float* __restrict__ attn,
                                                       float* __restrict__ rep) {
    __shared__ float zbuf[256];
    __shared__ float invZ[8];
    __shared__ float ctxp[2][128];
    __shared__ float ctx[128];
    __shared__ float seg[8][32];
    int t = threadIdx.x;
    int ck = blockIdx.x;     // 0..31
    int b = blockIdx.y;
    int a_rep = ck & 7, hq = ck >> 3;

    zbuf[t] = Zpart[((size_t)(b * AA + (t >> 5))) * 32 + (t & 31)];
    __syncthreads();
    if (t < 8) {
        float z = 0.f;
        #pragma unroll
        for (int k = 0; k < 32; ++k) z += zbuf[t * 32 + k];
        invZ[t] = 1.0f / z;
    }
    __syncthreads();

    for (int oi = t; oi < 512; oi += 256) {
        int a = oi >> 6, s = oi & 63;
        size_t idx = ((size_t)(b * AA + a)) * SS + ck * 64 + s;
        attn[idx] = E[idx] * invZ[a];
    }

    {
        int d = t & 127, half = t >> 7;
        float v = 0.f;
        for (int c = half * 16; c < half * 16 + 16; ++c)
            v += pools[(((size_t)(b * 32 + c)) * AA + a_rep) * HH + d];
        ctxp[half][d] = v;
    }
    __syncthreads();
    if (t < 128) ctx[t] = (ctxp[0][t] + ctxp[1][t]) * invZ[a_rep];
    __syncthreads();

    {
        int h = hq * 32 + (t & 31), sg = t >> 5;
        float v = 0.f;
        for (int d = sg * 16; d < sg * 16 + 16; ++d)
            v += ctx[d] * proj[((size_t)a_rep * HH + d) * HH + h];
        seg[sg][t & 31] = v;
    }
    __syncthreads();
    if (t < 32) {
        float v = 0.f;
        #pragma unroll
        for (int sg = 0; sg < 8; ++sg) v += seg[sg][t];
        rep[((size_t)(b * AA + a_rep)) * HH + hq * 32 + t] = v;
    }
}

extern "C" void kernel_launch(void* const* d_in, const int* in_sizes, int n_in,
                              void* d_out, int out_size, void* d_ws, size_t ws_size,
                              hipStream_t stream) {
    const float* doc   = (const float*)d_in[0];   // [32][2048][128]
    const int*   mask  = (const int*)d_in[1];     // [32][2048]
    const float* embed = (const float*)d_in[2];   // [8][384]
    const float* proj  = (const float*)d_in[3];   // [8][128][128]

    float* out  = (float*)d_out;
    float* attn = out;                             // [32][8][2048]
    float* rep  = out + (size_t)BB * AA * SS;      // [32][8][128]

    uint4* bfrag = (uint4*)d_ws;                   // 12288 B of the 16 KB slot
    float* E     = (float*)d_ws + 4096;
    float* Zp    = E + (size_t)BB * AA * SS;
    float* pools = Zp + (size_t)BB * AA * 32;

    prep_kernel<<<8, 128, 0, stream>>>(embed, proj, bfrag);
    tile_kernel<<<dim3(32, 32), 256, 0, stream>>>(doc, mask, bfrag, E, Zp, pools);
    finalize_kernel<<<dim3(32, 32), 256, 0, stream>>>(E, Zp, pools, proj, attn, rep);
}

// Round 14
// 27.315 us; speedup vs baseline: 1.3520x; 1.0608x over previous
//
#include <hip/hip_runtime.h>
#include <math.h>

#define BB 32
#define SS 2048
#define HH 128
#define AA 8

typedef _Float16 h2 __attribute__((ext_vector_type(2)));
typedef _Float16 h8 __attribute__((ext_vector_type(8)));
typedef _Float16 f16x8 __attribute__((ext_vector_type(8)));
typedef _Float16 f16x4 __attribute__((ext_vector_type(4)));
typedef float f32x4 __attribute__((ext_vector_type(4)));

// ws layout:
//   bfrag:  [12][64] uint4 (12288 B) — u prepacked as MFMA B-fragments:
//           bfrag[kk][lane] elem j = B[k][c], k = kk*32+(lane>>4)*8+j
//           (k = w*128+d), c = lane&15 (zero for c>=8)
//   E:      [B][A][S]     524288 floats (masked exp(score), unnormalized)
//   Zpart:  [B][A][32]    8192
//   pools:  [B][32][A][H] 1048576 (unnormalized partial context sums)

// R11-proven prep: 8 blocks x 128 threads.
__global__ __launch_bounds__(128) void prep_kernel(const float* __restrict__ embed,
                                                   const float* __restrict__ proj,
                                                   uint4* __restrict__ bfrag) {
    __shared__ float ua[HH][3];   // u for this aspect: [d][w]
    int a = blockIdx.x;           // 0..7
    int d = threadIdx.x;          // 0..127
    const float* P = proj + ((size_t)a * HH + d) * HH;  // aspProj[a][d][:]
    const float* E = embed + a * (3 * HH);              // embedR[a][h][w] = E[h*3+w]
    float a0 = 0.f, a1 = 0.f, a2 = 0.f;
    for (int h = 0; h < HH; ++h) {
        float x = P[h];
        a0 += x * E[h * 3 + 0];   // E loads wave-uniform -> scalar cache
        a1 += x * E[h * 3 + 1];
        a2 += x * E[h * 3 + 2];
    }
    ua[d][0] = a0; ua[d][1] = a1; ua[d][2] = a2;
    __syncthreads();

    for (int i = d; i < 96; i += 128) {
        int kk = i >> 3, e = i & 7;
        f16x8 v = {0, 0, 0, 0, 0, 0, 0, 0};
        int lane;
        if (e < 4) {
            int q = e;
            lane = q * 16 + a;
            #pragma unroll
            for (int j = 0; j < 8; ++j) {
                int k = kk * 32 + q * 8 + j;
                int w = k >> 7, dd = k & 127;
                v[j] = (_Float16)ua[dd][w];
            }
        } else {
            lane = (e - 4) * 16 + a + 8;   // zero columns 8..15
        }
        bfrag[kk * 64 + lane] = __builtin_bit_cast(uint4, v);
    }
}

// Per (b, 64-s tile): scores via 16x16x32 MFMA; E = mask*exp(score) (float4
// store); Zpart via in-register shfl reduce; pool via 16x16x16 MFMA whose
// A-fragment IS the score output in-register (D layout row=(l>>4)*4+reg,
// col=l&15 == A layout k=(l>>4)*4+j, m=l&15). Max-free exp safe (|score|<~0.2).
__global__ __launch_bounds__(256, 4) void tile_kernel(const float* __restrict__ doc,
                                                      const int* __restrict__ mask,
                                                      const uint4* __restrict__ bfrag,
                                                      float* __restrict__ E,
                                                      float* __restrict__ Zpart,
                                                      float* __restrict__ pools) {
    // dt [66][72] h2 (19008 B) + zredN [4][16] f32 (256 B); cs2 overlays dt.
    __shared__ __align__(16) unsigned char smraw[19264];
    h2*    dt    = (h2*)smraw;
    float* zredN = (float*)(smraw + 19008);

    int t = threadIdx.x;
    int lane = t & 63, wave = t >> 6;
    int tile = blockIdx.x;   // 0..31, 64 s each
    int b = blockIdx.y;
    int s0 = tile * 64;

    // ---- stage rows s0-1 .. s0+64 as f16 (zero outside [0,S)), stride 72 h2 ----
    for (int idx = t; idx < 66 * 16; idx += 256) {
        int row = idx >> 4, c = idx & 15;   // c: 8-float chunk
        int srow = s0 - 1 + row;
        h8 hv = {0, 0, 0, 0, 0, 0, 0, 0};
        if (srow >= 0 && srow < SS) {
            const float4* src = (const float4*)(doc + ((size_t)b * SS + srow) * HH + c * 8);
            float4 v0 = src[0], v1 = src[1];
            hv[0] = (_Float16)v0.x; hv[1] = (_Float16)v0.y;
            hv[2] = (_Float16)v0.z; hv[3] = (_Float16)v0.w;
            hv[4] = (_Float16)v1.x; hv[5] = (_Float16)v1.y;
            hv[6] = (_Float16)v1.z; hv[7] = (_Float16)v1.w;
        }
        *(h8*)(dt + row * 72 + c * 4) = hv;
    }

    // ---- B fragments for scores: 12 x 16B per lane (L2-hot) ----
    f16x8 bf[12];
    #pragma unroll
    for (int kk = 0; kk < 12; ++kk)
        bf[kk] = __builtin_bit_cast(f16x8, bfrag[kk * 64 + lane]);
    __syncthreads();   // dt ready

    // ---- scores: wave covers s rows wave*16 .. wave*16+15 ----
    f32x4 acc = {0.f, 0.f, 0.f, 0.f};
    #pragma unroll
    for (int kk = 0; kk < 12; ++kk) {
        int w = kk >> 2;
        int row = wave * 16 + (lane & 15) + w;
        int colh2 = (kk & 3) * 16 + (lane >> 4) * 4;
        f16x8 af = *(const f16x8*)(dt + row * 72 + colh2);
        acc = __builtin_amdgcn_mfma_f32_16x16x32_f16(af, bf[kk], acc, 0, 0, 0);
    }

    // ---- E write + in-register A-frag (af4) + in-register Z partial ----
    // D layout: col = lane&15 (aspect), row = (lane>>4)*4 + reg (s in 16-block)
    const int* mrow = mask + (size_t)b * SS + s0;
    int a = lane & 15;
    int rbase = wave * 16 + (lane >> 4) * 4;
    f16x4 af4;
    float4 ev;
    float* evp = (float*)&ev;
    float zsum = 0.f;
    #pragma unroll
    for (int jj = 0; jj < 4; ++jj) {
        int sl2 = rbase + jj;
        float e = (a < 8 && mrow[sl2]) ? __expf(acc[jj]) : 0.f;
        evp[jj] = e;
        af4[jj] = (_Float16)e;
        zsum += e;
    }
    if (a < 8)
        *(float4*)(E + ((size_t)(b * AA + a)) * SS + s0 + rbase) = ev;
    zsum += __shfl_xor(zsum, 16);   // combine the four (lane>>4) s-groups
    zsum += __shfl_xor(zsum, 32);
    if (lane < 16) zredN[wave * 16 + lane] = zsum;   // per-a per-wave Z

    // ---- pool MFMAs: per wave, K=16 (its own s), 8 d-tiles of 16 ----
    // A = af4 (in-register). B[k][n] at lane l: k=(l>>4)*4+j, n=l&15:
    // bfp[j] = dt[1 + rbase + j][dtile*16 + (l&15)]  (scalar u16 reads)
    const _Float16* dtf = (const _Float16*)dt;
    f32x4 pc[8];
    #pragma unroll
    for (int i = 0; i < 8; ++i) pc[i] = (f32x4){0.f, 0.f, 0.f, 0.f};
    int srow0 = 1 + rbase;
    #pragma unroll
    for (int dtile = 0; dtile < 8; ++dtile) {
        f16x4 bfp;
        #pragma unroll
        for (int j = 0; j < 4; ++j)
            bfp[j] = dtf[(srow0 + j) * 144 + dtile * 16 + a];
        pc[dtile] = __builtin_amdgcn_mfma_f32_16x16x16f16(af4, bfp, pc[dtile], 0, 0, 0);
    }
    __syncthreads();   // all dt reads + all zredN writes done

    // pool D layout: col = lane&15 = d_in_tile, row = (lane>>4)*4+reg = a
    float* cs2 = (float*)smraw;   // [4 wave][8 a][128 d] = 16384 B < 19008
    if ((lane >> 4) < 2) {
        int ab = (lane >> 4) * 4;
        #pragma unroll
        for (int dtile = 0; dtile < 8; ++dtile) {
            int d = dtile * 16 + a;
            #pragma unroll
            for (int r = 0; r < 4; ++r)
                cs2[wave * 1024 + (ab + r) * 128 + d] = pc[dtile][r];
        }
    }
    if (t < 8) {
        float z = (zredN[0 * 16 + t] + zredN[1 * 16 + t]) +
                  (zredN[2 * 16 + t] + zredN[3 * 16 + t]);
        Zpart[((size_t)(b * AA + t)) * 32 + tile] = z;
    }
    __syncthreads();
    for (int oi = t; oi < 1024; oi += 256) {
        int aa = oi >> 7, d = oi & 127;
        float v = (cs2[0 * 1024 + aa * 128 + d] + cs2[1 * 1024 + aa * 128 + d]) +
                  (cs2[2 * 1024 + aa * 128 + d] + cs2[3 * 1024 + aa * 128 + d]);
        pools[(((size_t)(b * 32 + tile)) * AA + aa) * HH + d] = v;
    }
}

// R11-proven finalize: per (b, chunk): invZ from Zpart; attn = E*invZ for the
// 64-s chunk; plus a 32-h slice of rep for aspect a = chunk&7 (hq = chunk>>3).
__global__ __launch_bounds__(256) void finalize_kernel(const float* __restrict__ E,
                                                       const float* __restrict__ Zpart,
                                                       const float* __restrict__ pools,
                                                       const float* __restrict__ proj,
                                                       float* __restrict__ attn,
                                                       float* __restrict__ rep) {
    __shared__ float zbuf[256];
    __shared__ float invZ[8];
    __shared__ float ctxp[2][128];
    __shared__ float ctx[128];
    __shared__ float seg[8][32];
    int t = threadIdx.x;
    int ck = blockIdx.x;     // 0..31
    int b = blockIdx.y;
    int a_rep = ck & 7, hq = ck >> 3;

    zbuf[t] = Zpart[((size_t)(b * AA + (t >> 5))) * 32 + (t & 31)];
    __syncthreads();
    if (t < 8) {
        float z = 0.f;
        #pragma unroll
        for (int k = 0; k < 32; ++k) z += zbuf[t * 32 + k];
        invZ[t] = 1.0f / z;
    }
    __syncthreads();

    for (int oi = t; oi < 512; oi += 256) {
        int a = oi >> 6, s = oi & 63;
        size_t idx = ((size_t)(b * AA + a)) * SS + ck * 64 + s;
        attn[idx] = E[idx] * invZ[a];
    }

    {
        int d = t & 127, half = t >> 7;
        float v = 0.f;
        for (int c = half * 16; c < half * 16 + 16; ++c)
            v += pools[(((size_t)(b * 32 + c)) * AA + a_rep) * HH + d];
        ctxp[half][d] = v;
    }
    __syncthreads();
    if (t < 128) ctx[t] = (ctxp[0][t] + ctxp[1][t]) * invZ[a_rep];
    __syncthreads();

    {
        int h = hq * 32 + (t & 31), sg = t >> 5;
        float v = 0.f;
        for (int d = sg * 16; d < sg * 16 + 16; ++d)
            v += ctx[d] * proj[((size_t)a_rep * HH + d) * HH + h];
        seg[sg][t & 31] = v;
    }
    __syncthreads();
    if (t < 32) {
        float v = 0.f;
        #pragma unroll
        for (int sg = 0; sg < 8; ++sg) v += seg[sg][t];
        rep[((size_t)(b * AA + a_rep)) * HH + hq * 32 + t] = v;
    }
}

extern "C" void kernel_launch(void* const* d_in, const int* in_sizes, int n_in,
                              void* d_out, int out_size, void* d_ws, size_t ws_size,
                              hipStream_t stream) {
    const float* doc   = (const float*)d_in[0];   // [32][2048][128]
    const int*   mask  = (const int*)d_in[1];     // [32][2048]
    const float* embed = (const float*)d_in[2];   // [8][384]
    const float* proj  = (const float*)d_in[3];   // [8][128][128]

    float* out  = (float*)d_out;
    float* attn = out;                             // [32][8][2048]
    float* rep  = out + (size_t)BB * AA * SS;      // [32][8][128]

    uint4* bfrag = (uint4*)d_ws;                   // 12288 B of the 16 KB slot
    float* E     = (float*)d_ws + 4096;
    float* Zp    = E + (size_t)BB * AA * SS;
    float* pools = Zp + (size_t)BB * AA * 32;

    prep_kernel<<<8, 128, 0, stream>>>(embed, proj, bfrag);
    tile_kernel<<<dim3(32, 32), 256, 0, stream>>>(doc, mask, bfrag, E, Zp, pools);
    finalize_kernel<<<dim3(32, 32), 256, 0, stream>>>(E, Zp, pools, proj, attn, rep);
}